// Round 3
// baseline (213.509 us; speedup 1.0000x reference)
//
#include <hip/hip_runtime.h>

// WellTemparedMetaDynamics: B=32, H=200000, D=8
// eng[b]    = sum_h hgt_h[b,h] * exp(-0.5 * sum_d (cen-col)^2 * prc_h)
// new_hgt[b]= hgt * exp(-eng[b] / (kbt[b]*(gam-1)))
// outputs: cen_out (B,H+1,D) | prc_out (B,H+1,D) | hgt_out (B,H+1)  (flat concat)

#define BB 32
#define HH 200000
#define DD 8
#define HPT 8      // hills per thread in the main kernel
#define BLK 256    // threads per block

typedef float f32x4 __attribute__((ext_vector_type(4)));

// Fused pass: copy cen/prc_h/hgt_h into (H+1)-strided outputs AND reduce
// per-batch energy into deterministic per-block partials in d_ws.
__global__ __launch_bounds__(BLK) void wtmtd_main(
    const float* __restrict__ col,
    const float* __restrict__ cen,
    const float* __restrict__ prc_h,
    const float* __restrict__ hgt_h,
    float* __restrict__ cen_out,
    float* __restrict__ prc_out,
    float* __restrict__ hgt_out,
    float* __restrict__ partials)
{
    const int b = blockIdx.y;

    const f32x4* colv = (const f32x4*)(col + (size_t)b * DD);
    const f32x4 c0 = colv[0];
    const f32x4 c1 = colv[1];

    const size_t inBase  = (size_t)b * HH;
    const size_t outBase = (size_t)b * (HH + 1);

    float local = 0.0f;
    const int h0 = blockIdx.x * (BLK * HPT) + threadIdx.x;
    const bool full = (blockIdx.x + 1) * (BLK * HPT) <= HH;   // block-uniform

    if (full) {
        #pragma unroll
        for (int i = 0; i < HPT; ++i) {
            const int h = h0 + i * BLK;
            const f32x4* cen4 = (const f32x4*)(cen   + (inBase + h) * DD);
            const f32x4* prc4 = (const f32x4*)(prc_h + (inBase + h) * DD);
            const f32x4 a0 = __builtin_nontemporal_load(cen4 + 0);
            const f32x4 a1 = __builtin_nontemporal_load(cen4 + 1);
            const f32x4 p0 = __builtin_nontemporal_load(prc4 + 0);
            const f32x4 p1 = __builtin_nontemporal_load(prc4 + 1);
            const float hh  = __builtin_nontemporal_load(hgt_h + inBase + h);

            float r, s;
            r = a0.x - c0.x; s  = r * r * p0.x;
            r = a0.y - c0.y; s += r * r * p0.y;
            r = a0.z - c0.z; s += r * r * p0.z;
            r = a0.w - c0.w; s += r * r * p0.w;
            r = a1.x - c1.x; s += r * r * p1.x;
            r = a1.y - c1.y; s += r * r * p1.y;
            r = a1.z - c1.z; s += r * r * p1.z;
            r = a1.w - c1.w; s += r * r * p1.w;

            local += hh * expf(-0.5f * s);

            f32x4* co = (f32x4*)(cen_out + (outBase + h) * DD);
            __builtin_nontemporal_store(a0, co + 0);
            __builtin_nontemporal_store(a1, co + 1);
            f32x4* po = (f32x4*)(prc_out + (outBase + h) * DD);
            __builtin_nontemporal_store(p0, po + 0);
            __builtin_nontemporal_store(p1, po + 1);
            __builtin_nontemporal_store(hh, hgt_out + outBase + h);
        }
    } else {
        #pragma unroll
        for (int i = 0; i < HPT; ++i) {
            const int h = h0 + i * BLK;
            if (h < HH) {
                const f32x4* cen4 = (const f32x4*)(cen   + (inBase + h) * DD);
                const f32x4* prc4 = (const f32x4*)(prc_h + (inBase + h) * DD);
                const f32x4 a0 = __builtin_nontemporal_load(cen4 + 0);
                const f32x4 a1 = __builtin_nontemporal_load(cen4 + 1);
                const f32x4 p0 = __builtin_nontemporal_load(prc4 + 0);
                const f32x4 p1 = __builtin_nontemporal_load(prc4 + 1);
                const float hh  = __builtin_nontemporal_load(hgt_h + inBase + h);

                float r, s;
                r = a0.x - c0.x; s  = r * r * p0.x;
                r = a0.y - c0.y; s += r * r * p0.y;
                r = a0.z - c0.z; s += r * r * p0.z;
                r = a0.w - c0.w; s += r * r * p0.w;
                r = a1.x - c1.x; s += r * r * p1.x;
                r = a1.y - c1.y; s += r * r * p1.y;
                r = a1.z - c1.z; s += r * r * p1.z;
                r = a1.w - c1.w; s += r * r * p1.w;

                local += hh * expf(-0.5f * s);

                f32x4* co = (f32x4*)(cen_out + (outBase + h) * DD);
                __builtin_nontemporal_store(a0, co + 0);
                __builtin_nontemporal_store(a1, co + 1);
                f32x4* po = (f32x4*)(prc_out + (outBase + h) * DD);
                __builtin_nontemporal_store(p0, po + 0);
                __builtin_nontemporal_store(p1, po + 1);
                __builtin_nontemporal_store(hh, hgt_out + outBase + h);
            }
        }
    }

    // wave64 shuffle reduce, then cross-wave via LDS
    #pragma unroll
    for (int off = 32; off > 0; off >>= 1)
        local += __shfl_down(local, off);

    __shared__ float sred[BLK / 64];
    const int lane = threadIdx.x & 63;
    const int wv   = threadIdx.x >> 6;
    if (lane == 0) sred[wv] = local;
    __syncthreads();
    if (threadIdx.x == 0) {
        float s = 0.0f;
        #pragma unroll
        for (int i = 0; i < BLK / 64; ++i) s += sred[i];
        partials[(size_t)b * gridDim.x + blockIdx.x] = s;
    }
}

// Final: reduce partials (fixed order -> deterministic), compute new hill,
// write the appended slot H for all three outputs.
__global__ __launch_bounds__(64) void wtmtd_fin(
    const float* __restrict__ partials, int nblk,
    const float* __restrict__ col,
    const float* __restrict__ kbt,
    const float* __restrict__ prc,
    const float* __restrict__ hgt,
    const float* __restrict__ gam,
    float* __restrict__ cen_out,
    float* __restrict__ prc_out,
    float* __restrict__ hgt_out)
{
    const int b = blockIdx.x;

    float s = 0.0f;
    for (int i = threadIdx.x; i < nblk; i += 64)
        s += partials[(size_t)b * nblk + i];
    #pragma unroll
    for (int off = 32; off > 0; off >>= 1)
        s += __shfl_down(s, off);
    s = __shfl(s, 0);   // broadcast eng[b]

    const float det = kbt[b] * (gam[0] - 1.0f);
    const float new_hgt = hgt[0] * expf(-s / det);

    const size_t outBase = (size_t)b * (HH + 1);
    if (threadIdx.x < DD) {
        cen_out[(outBase + HH) * DD + threadIdx.x] = col[(size_t)b * DD + threadIdx.x];
        prc_out[(outBase + HH) * DD + threadIdx.x] = prc[threadIdx.x];
    }
    if (threadIdx.x == 0)
        hgt_out[outBase + HH] = new_hgt;
}

extern "C" void kernel_launch(void* const* d_in, const int* in_sizes, int n_in,
                              void* d_out, int out_size, void* d_ws, size_t ws_size,
                              hipStream_t stream) {
    const float* col   = (const float*)d_in[0];
    const float* cen   = (const float*)d_in[1];
    const float* prc_h = (const float*)d_in[2];
    const float* hgt_h = (const float*)d_in[3];
    const float* kbt   = (const float*)d_in[4];
    const float* prc   = (const float*)d_in[5];
    const float* hgt   = (const float*)d_in[6];
    const float* gam   = (const float*)d_in[7];

    float* cen_out = (float*)d_out;
    float* prc_out = cen_out + (size_t)BB * (HH + 1) * DD;
    float* hgt_out = prc_out + (size_t)BB * (HH + 1) * DD;

    float* partials = (float*)d_ws;

    const int nblk = (HH + BLK * HPT - 1) / (BLK * HPT);  // 98
    dim3 grid(nblk, BB);

    wtmtd_main<<<grid, BLK, 0, stream>>>(col, cen, prc_h, hgt_h,
                                         cen_out, prc_out, hgt_out, partials);
    wtmtd_fin<<<BB, 64, 0, stream>>>(partials, nblk, col, kbt, prc, hgt, gam,
                                     cen_out, prc_out, hgt_out);
}

// Round 4
// 181.315 us; speedup vs baseline: 1.1776x; 1.1776x over previous
//
#include <hip/hip_runtime.h>

// WellTemparedMetaDynamics: B=32, H=200000, D=8
// eng[b]    = sum_h hgt_h[b,h] * exp(-0.5 * sum_d (cen-col)^2 * prc_h)
// new_hgt[b]= hgt * exp(-eng[b] / (kbt[b]*(gam-1)))
// outputs: cen_out (B,H+1,D) | prc_out (B,H+1,D) | hgt_out (B,H+1)  (flat concat)

#define BB 32
#define HH 200000
#define DD 8
#define HPT 8      // hills per thread in the main kernel
#define BLK 256    // threads per block

typedef float f32x4 __attribute__((ext_vector_type(4)));

// Fused pass: copy cen/prc_h/hgt_h into (H+1)-strided outputs AND reduce
// per-batch energy into deterministic per-block partials in d_ws.
// Plain (cached) loads/stores: L2 write-combining is required for the
// 32B-misaligned per-batch output streams (nt stores regressed 186->213 us).
__global__ __launch_bounds__(BLK) void wtmtd_main(
    const float* __restrict__ col,
    const float* __restrict__ cen,
    const float* __restrict__ prc_h,
    const float* __restrict__ hgt_h,
    float* __restrict__ cen_out,
    float* __restrict__ prc_out,
    float* __restrict__ hgt_out,
    float* __restrict__ partials)
{
    const int b = blockIdx.y;

    const f32x4* colv = (const f32x4*)(col + (size_t)b * DD);
    const f32x4 c0 = colv[0];
    const f32x4 c1 = colv[1];

    const size_t inBase  = (size_t)b * HH;
    const size_t outBase = (size_t)b * (HH + 1);

    float local = 0.0f;
    const int h0 = blockIdx.x * (BLK * HPT) + threadIdx.x;
    const bool full = (blockIdx.x + 1) * (BLK * HPT) <= HH;   // block-uniform

    if (full) {
        #pragma unroll
        for (int i = 0; i < HPT; ++i) {
            const int h = h0 + i * BLK;
            const f32x4* cen4 = (const f32x4*)(cen   + (inBase + h) * DD);
            const f32x4* prc4 = (const f32x4*)(prc_h + (inBase + h) * DD);
            const f32x4 a0 = cen4[0];
            const f32x4 a1 = cen4[1];
            const f32x4 p0 = prc4[0];
            const f32x4 p1 = prc4[1];
            const float hh = hgt_h[inBase + h];

            float r, s;
            r = a0.x - c0.x; s  = r * r * p0.x;
            r = a0.y - c0.y; s += r * r * p0.y;
            r = a0.z - c0.z; s += r * r * p0.z;
            r = a0.w - c0.w; s += r * r * p0.w;
            r = a1.x - c1.x; s += r * r * p1.x;
            r = a1.y - c1.y; s += r * r * p1.y;
            r = a1.z - c1.z; s += r * r * p1.z;
            r = a1.w - c1.w; s += r * r * p1.w;

            local += hh * __expf(-0.5f * s);   // 2-instr exp; only feeds hgt_out[H]

            f32x4* co = (f32x4*)(cen_out + (outBase + h) * DD);
            co[0] = a0; co[1] = a1;
            f32x4* po = (f32x4*)(prc_out + (outBase + h) * DD);
            po[0] = p0; po[1] = p1;
            hgt_out[outBase + h] = hh;
        }
    } else {
        #pragma unroll
        for (int i = 0; i < HPT; ++i) {
            const int h = h0 + i * BLK;
            if (h < HH) {
                const f32x4* cen4 = (const f32x4*)(cen   + (inBase + h) * DD);
                const f32x4* prc4 = (const f32x4*)(prc_h + (inBase + h) * DD);
                const f32x4 a0 = cen4[0];
                const f32x4 a1 = cen4[1];
                const f32x4 p0 = prc4[0];
                const f32x4 p1 = prc4[1];
                const float hh = hgt_h[inBase + h];

                float r, s;
                r = a0.x - c0.x; s  = r * r * p0.x;
                r = a0.y - c0.y; s += r * r * p0.y;
                r = a0.z - c0.z; s += r * r * p0.z;
                r = a0.w - c0.w; s += r * r * p0.w;
                r = a1.x - c1.x; s += r * r * p1.x;
                r = a1.y - c1.y; s += r * r * p1.y;
                r = a1.z - c1.z; s += r * r * p1.z;
                r = a1.w - c1.w; s += r * r * p1.w;

                local += hh * __expf(-0.5f * s);

                f32x4* co = (f32x4*)(cen_out + (outBase + h) * DD);
                co[0] = a0; co[1] = a1;
                f32x4* po = (f32x4*)(prc_out + (outBase + h) * DD);
                po[0] = p0; po[1] = p1;
                hgt_out[outBase + h] = hh;
            }
        }
    }

    // wave64 shuffle reduce, then cross-wave via LDS
    #pragma unroll
    for (int off = 32; off > 0; off >>= 1)
        local += __shfl_down(local, off);

    __shared__ float sred[BLK / 64];
    const int lane = threadIdx.x & 63;
    const int wv   = threadIdx.x >> 6;
    if (lane == 0) sred[wv] = local;
    __syncthreads();
    if (threadIdx.x == 0) {
        float s = 0.0f;
        #pragma unroll
        for (int i = 0; i < BLK / 64; ++i) s += sred[i];
        partials[(size_t)b * gridDim.x + blockIdx.x] = s;
    }
}

// Final: reduce partials (fixed order -> deterministic), compute new hill,
// write the appended slot H for all three outputs.
__global__ __launch_bounds__(64) void wtmtd_fin(
    const float* __restrict__ partials, int nblk,
    const float* __restrict__ col,
    const float* __restrict__ kbt,
    const float* __restrict__ prc,
    const float* __restrict__ hgt,
    const float* __restrict__ gam,
    float* __restrict__ cen_out,
    float* __restrict__ prc_out,
    float* __restrict__ hgt_out)
{
    const int b = blockIdx.x;

    float s = 0.0f;
    for (int i = threadIdx.x; i < nblk; i += 64)
        s += partials[(size_t)b * nblk + i];
    #pragma unroll
    for (int off = 32; off > 0; off >>= 1)
        s += __shfl_down(s, off);
    s = __shfl(s, 0);   // broadcast eng[b]

    const float det = kbt[b] * (gam[0] - 1.0f);
    const float new_hgt = hgt[0] * expf(-s / det);

    const size_t outBase = (size_t)b * (HH + 1);
    if (threadIdx.x < DD) {
        cen_out[(outBase + HH) * DD + threadIdx.x] = col[(size_t)b * DD + threadIdx.x];
        prc_out[(outBase + HH) * DD + threadIdx.x] = prc[threadIdx.x];
    }
    if (threadIdx.x == 0)
        hgt_out[outBase + HH] = new_hgt;
}

extern "C" void kernel_launch(void* const* d_in, const int* in_sizes, int n_in,
                              void* d_out, int out_size, void* d_ws, size_t ws_size,
                              hipStream_t stream) {
    const float* col   = (const float*)d_in[0];
    const float* cen   = (const float*)d_in[1];
    const float* prc_h = (const float*)d_in[2];
    const float* hgt_h = (const float*)d_in[3];
    const float* kbt   = (const float*)d_in[4];
    const float* prc   = (const float*)d_in[5];
    const float* hgt   = (const float*)d_in[6];
    const float* gam   = (const float*)d_in[7];

    float* cen_out = (float*)d_out;
    float* prc_out = cen_out + (size_t)BB * (HH + 1) * DD;
    float* hgt_out = prc_out + (size_t)BB * (HH + 1) * DD;

    float* partials = (float*)d_ws;

    const int nblk = (HH + BLK * HPT - 1) / (BLK * HPT);  // 98
    dim3 grid(nblk, BB);

    wtmtd_main<<<grid, BLK, 0, stream>>>(col, cen, prc_h, hgt_h,
                                         cen_out, prc_out, hgt_out, partials);
    wtmtd_fin<<<BB, 64, 0, stream>>>(partials, nblk, col, kbt, prc, hgt, gam,
                                     cen_out, prc_out, hgt_out);
}